// Round 22
// baseline (340.402 us; speedup 1.0000x reference)
//
#include <hip/hip_runtime.h>
#include <hip/hip_bf16.h>
#include <stdint.h>

// ---------- types / helpers ----------
typedef short short8 __attribute__((ext_vector_type(8)));   // 8 x bf16 (4 VGPRs) MFMA frag
typedef float f32x4  __attribute__((ext_vector_type(4)));   // MFMA C/D frag

__device__ __forceinline__ uint16_t f2bf(float f) {
    union { float f; uint32_t u; } v; v.f = f;
    return (uint16_t)((v.u + 0x7FFFu + ((v.u >> 16) & 1u)) >> 16);  // RNE
}
__device__ __forceinline__ float bf2f(uint16_t h) {
    union { uint32_t u; float f; } v; v.u = ((uint32_t)h) << 16;
    return v.f;
}
// pack 2 f32 -> 2 bf16 in one VALU op (lo = a, hi = b)
__device__ __forceinline__ uint32_t pk2bf(float a, float b) {
    uint32_t r;
    asm("v_cvt_pk_bf16_f32 %0, %1, %2" : "=v"(r) : "v"(a), "v"(b));
    return r;
}
// async global->LDS, 16B per lane. LDS dest must be wave-uniform base + lane*16.
__device__ __forceinline__ void gl_lds16(const void* g, void* l) {
    __builtin_amdgcn_global_load_lds(
        (const __attribute__((address_space(1))) unsigned int*)g,
        (__attribute__((address_space(3))) unsigned int*)l, 16, 0, 0);
}

#define NSAMP_TOT 32768
// h2 LOGICAL layout: [s][k'], k' = (p/16)*512 + c*16 + (p%16), K padded to 5120.
// h2 PHYSICAL: within each 64-elem K-window, 8-elem chunk q holds logical chunk q ^ (s&7).
// w1pt PHYSICAL: within each 64-elem K-window, chunk q holds logical chunk q ^ (n&7).
#define H2_PER_S  5120

// ---------- K0: all weight repacks in one dispatch (169 blocks) ----------
__global__ void repack_all(const float* __restrict__ f1w, const float* __restrict__ c2w,
                           const float* __restrict__ c1w, const float* __restrict__ f2w,
                           uint16_t* __restrict__ w1pt, uint16_t* __restrict__ w2rt,
                           uint16_t* __restrict__ w1rt, uint16_t* __restrict__ w2bt) {
    int tid = threadIdx.x, b = blockIdx.x;
    if (b < 160) {
        int f_s = b >> 4, cp = b & 15, n = tid;
        __align__(16) uint16_t vals[32];
        #pragma unroll
        for (int o = 0; o < 32; o++) {
            int c = cp * 2 + (o >> 4), pl = o & 15;
            int p = f_s * 16 + pl;
            float v = (p < 150) ? f1w[(size_t)(c * 150 + p) * 256 + n] : 0.f;  // coalesced over n
            vals[o] = f2bf(v);
        }
        int win = f_s * 8 + (cp >> 1);
        size_t rowbase = (size_t)n * H2_PER_S + win * 64;
        #pragma unroll
        for (int j = 0; j < 4; j++) {
            int qlog = (cp * 4 + j) & 7;
            int qphy = qlog ^ (n & 7);
            *(uint4*)&w1pt[rowbase + qphy * 8] = *(uint4*)&vals[j * 8];
        }
    } else if (b == 160) {
        for (int t = tid; t < 32 * 160; t += 256) {
            int n = t / 160, k = t % 160;
            float v = 0.f;
            if (k < 144) {
                int tap = k >> 4, ci = k & 15, dy = tap / 3, dx = tap % 3;
                v = c2w[((n * 16 + ci) * 3 + dy) * 3 + dx];
            }
            w2rt[t] = f2bf(v);
        }
        for (int t = tid; t < 16 * 32; t += 256) {
            int n = t >> 5, k = t & 31;
            float v = 0.f;
            if (k < 18) {
                int tap = k >> 1, ch = k & 1;
                int dy = (tap * 11) >> 5, dx = tap - dy * 3;
                v = c1w[((n * 2 + ch) * 3 + dy) * 3 + dx];
            }
            w1rt[t] = f2bf(v);
        }
    } else {
        __shared__ float tr2[32][129];
        int kb = b - 161;                         // 0..7
        for (int i = tid; i < 32 * 128; i += 256) {
            int kk = i >> 7, n = i & 127;
            tr2[kk][n] = f2w[(size_t)(kb * 32 + kk) * 128 + n];
        }
        __syncthreads();
        int n = tid >> 1, half = tid & 1;
        __align__(16) uint16_t tmp[16];
        #pragma unroll
        for (int q = 0; q < 16; q++) tmp[q] = f2bf(tr2[half * 16 + q][n]);
        *(uint4*)&w2bt[(size_t)n * 256 + kb * 32 + half * 16]     = *(uint4*)&tmp[0];
        *(uint4*)&w2bt[(size_t)n * 256 + kb * 32 + half * 16 + 8] = *(uint4*)&tmp[8];
    }
}

// ---------- K12: grid scatter + conv1 MFMA + conv2 MFMA + relu -> h2 (swizzled chunks) ----------
// 8 samples/block, 512 threads (8 waves). WAVE w OWNS SAMPLE w. LUTs replace divisions.
// HBM-write-bound at ~4.7 TB/s -- at ceiling.
__launch_bounds__(512, 2)
__global__ void k12_fused(const float* __restrict__ x, const uint16_t* __restrict__ w1rt,
                          const float* __restrict__ c1b, const uint16_t* __restrict__ w2rt,
                          const float* __restrict__ c2b, uint16_t* __restrict__ h2, int s0) {
    __shared__ float sx[8 * 42];                           // 1344 B
    __shared__ __align__(16) uint16_t grd[8 * 204 * 2];    // 6528 B  = 408 uint4
    __shared__ __align__(16) uint16_t h1s[8 * 205 * 16];   // 52480 B = 3280 uint4
    __shared__ uint16_t lutPO[160];
    __shared__ uint16_t lutST[160];
    int tid = threadIdx.x;
    int w = tid >> 6, l = tid & 63, lr = l & 15, lk = l >> 4;

    short8 b1f = *(const short8*)&w1rt[lr * 32 + lk * 8];
    short8 bfr[5][2];
    #pragma unroll
    for (int ks = 0; ks < 5; ks++)
        #pragma unroll
        for (int nf = 0; nf < 2; nf++)
            bfr[ks][nf] = *(const short8*)&w2rt[(nf * 16 + lr) * 160 + ks * 32 + lk * 8];
    float cb1r = c1b[lr];
    float cb0 = c2b[lr], cb1 = c2b[16 + lr];

    uint4 z4 = make_uint4(0, 0, 0, 0);
    for (int idx = tid; idx < 3688; idx += 512) {
        if (idx < 408) ((uint4*)grd)[idx] = z4;
        else           ((uint4*)h1s)[idx - 408] = z4;
    }
    int sbase = s0 + blockIdx.x * 8;
    if (tid < 336) sx[tid] = x[(size_t)(sbase + tid / 42) * 42 + (tid % 42)];
    if (tid >= 336 && tid < 496) {
        int p = tid - 336;
        int y = p / 15, xx = p - y * 15;
        int po = y * 17 + xx;
        lutPO[p] = (p < 150) ? (uint16_t)po : 0;
        lutST[p] = (p < 150) ? (uint16_t)((po + 18) * 16) : (uint16_t)(204 * 16);
    }
    __syncthreads();

    if (tid < 160) {
        int sl = tid / 20, r = tid % 20;
        int kx = (int)sx[sl * 42 + 1 + 2 * r];
        int ky = (int)sx[sl * 42 + 2 + 2 * r];
        if (kx >= 0 && kx < 15 && ky >= 0 && ky < 10)
            grd[(sl * 204 + (ky + 1) * 17 + (kx + 1)) * 2 + 1] = 0x3F80;  // 1.0 bf16
    } else if (tid < 168) {
        int sl = tid - 160;
        int ry = (int)sx[sl * 42];
        if (ry >= 0 && ry < 10)
            grd[(sl * 204 + (ry + 1) * 17 + 2) * 2 + 0] = 0x3F80;
    }
    __syncthreads();

    int goff[4]; uint32_t gmask[4];
    #pragma unroll
    for (int jj = 0; jj < 4; jj++) {
        int t = lk * 4 + jj;
        int tc = t < 9 ? t : 0;
        int dy = (tc * 11) >> 5, dx = tc - dy * 3;
        goff[jj] = dy * 17 + dx;
        gmask[jj] = (t < 9) ? 0xFFFFFFFFu : 0u;
    }
    int sbg  = w * 204;
    int sb16 = w * 205 * 16;

    #pragma unroll
    for (int f_s = 0; f_s < 10; f_s++) {
        int p160 = f_s * 16 + lr;
        int gbase = sbg + lutPO[p160];
        union { uint32_t d[4]; short8 s; } au;
        #pragma unroll
        for (int jj = 0; jj < 4; jj++) {
            uint32_t v = *(const uint32_t*)&grd[(gbase + goff[jj]) * 2];
            au.d[jj] = v & gmask[jj];
        }
        f32x4 acc = {};
        acc = __builtin_amdgcn_mfma_f32_16x16x32_bf16(au.s, b1f, acc, 0, 0, 0);
        #pragma unroll
        for (int j = 0; j < 4; j += 2) {
            float v0 = fmaxf(acc[j] + cb1r, 0.f);
            float v1 = fmaxf(acc[j + 1] + cb1r, 0.f);
            uint32_t pk = pk2bf(v0, v1);
            int p2 = f_s * 16 + lk * 4 + j;
            h1s[sb16 + lutST[p2] + lr]     = (uint16_t)pk;
            h1s[sb16 + lutST[p2 + 1] + lr] = (uint16_t)(pk >> 16);
        }
    }
    __syncthreads();

    int cdofs[5];
    #pragma unroll
    for (int ks = 0; ks < 5; ks++) {
        int idx = ks * 4 + lk;
        int idc = idx < 18 ? idx : 0;
        int tap = idc >> 1, half = idc & 1;
        int dy = (tap * 11) >> 5, dx = tap - dy * 3;
        cdofs[ks] = (dy * 17 + dx) * 16 + half * 8;
    }
    uint32_t kmask4 = ((16 + lk) < 18) ? 0xFFFFFFFFu : 0u;
    int k0lo = lr * 16 + lk * 4;
    int k0s_base = (k0lo & ~63) | ((((k0lo >> 3) & 7) ^ w) << 3) | (k0lo & 7);
    size_t sbh2 = (size_t)(blockIdx.x * 8 + w) * H2_PER_S;

    #pragma unroll
    for (int f_s = 0; f_s < 10; f_s++) {
        int p160 = f_s * 16 + lr;
        int abase = sb16 + lutPO[p160] * 16;
        f32x4 acc0 = {}, acc1 = {};
        #pragma unroll
        for (int ks = 0; ks < 5; ks++) {
            short8 av = *(const short8*)&h1s[abase + cdofs[ks]];
            if (ks == 4) {
                union { short8 s; uint32_t d[4]; } u; u.s = av;
                #pragma unroll
                for (int dd = 0; dd < 4; dd++) u.d[dd] &= kmask4;
                av = u.s;
            }
            acc0 = __builtin_amdgcn_mfma_f32_16x16x32_bf16(av, bfr[ks][0], acc0, 0, 0, 0);
            acc1 = __builtin_amdgcn_mfma_f32_16x16x32_bf16(av, bfr[ks][1], acc1, 0, 0, 0);
        }
        uint32_t p01 = pk2bf(fmaxf(acc0[0] + cb0, 0.f), fmaxf(acc0[1] + cb0, 0.f));
        uint32_t p23 = pk2bf(fmaxf(acc0[2] + cb0, 0.f), fmaxf(acc0[3] + cb0, 0.f));
        uint32_t q01 = pk2bf(fmaxf(acc1[0] + cb1, 0.f), fmaxf(acc1[1] + cb1, 0.f));
        uint32_t q23 = pk2bf(fmaxf(acc1[2] + cb1, 0.f), fmaxf(acc1[3] + cb1, 0.f));
        int k0s = f_s * 512 + k0s_base;
        *(uint2*)&h2[sbh2 + k0s]       = make_uint2(p01, p23);
        *(uint2*)&h2[sbh2 + k0s + 256] = make_uint2(q01, q23);
    }
}

// ---------- K3: fc1 (32x256, K=5120; A tiny LDS dbuf, B direct regs, 2 blocks/CU) ----------
// grid = chunk/32 = 512 blocks = 2 blocks/CU (the measured lever: per-kt barrier quantum
// halves with a co-resident block). 512 threads = 8 waves, each owns all 32 rows x a
// DISTINCT 32-col group (acc[2][2], 8 MFMA/kt). Per kt: waves 0-3 stage A (4KB gl_lds),
// every thread loads 4 B 16B-frags to registers (dbuf b0/b1). LDS ~24KB, low VGPR.
__launch_bounds__(512, 4)
__global__ void k3_fused(const uint16_t* __restrict__ h2, const uint16_t* __restrict__ w1pt,
                         const float* __restrict__ f1b, const float* __restrict__ f1w,
                         const float* __restrict__ x, const uint16_t* __restrict__ w2bt,
                         const float* __restrict__ f2b, const float* __restrict__ f3w,
                         const float* __restrict__ f3b, float* __restrict__ out, int s0) {
    __shared__ __align__(16) uint16_t uLDS[32 * 256];   // 16 KB: lA0|lA1 in loop; lH after
    uint16_t* lA0 = uLDS;                // 32 x 64 (2048 elems)
    uint16_t* lA1 = uLDS + 2048;
    uint16_t* lH  = uLDS;                // 32 x 256 epilogue reuse
    __shared__ float sbias[256], swl[256], sspeed[32], sb2[128], sw3[384];
    __shared__ float pf[4][32][3];
    int tid = threadIdx.x;
    int bm = blockIdx.x;
    if (tid < 256) { sbias[tid] = f1b[tid]; swl[tid] = f1w[(size_t)4800 * 256 + tid]; }
    else if (tid < 288) sspeed[tid - 256] = x[(size_t)(s0 + bm * 32 + (tid - 256)) * 42 + 41];
    else if (tid < 416) sb2[tid - 288] = f2b[tid - 288];
    for (int i = tid; i < 384; i += 512) sw3[i] = f3w[i];

    int w = tid >> 6, l = tid & 63, lr = l & 15, lk = l >> 4;
    int wm = w >> 2, wn = w & 3;     // epilogue fc2/fc3 tiling
    // A staging: 256 chunks (32 rows x 8) -- waves 0..3 only
    const uint16_t* ga = &h2[(size_t)(bm * 32 + ((tid & 255) >> 3)) * H2_PER_S + (tid & 7) * 8];
    int saOff = (tid & 255) * 8;
    bool stager = (tid < 256);
    // B fragment global pointers (per-lane, deswizzled); advance +64/kt
    const uint16_t* gB[2][2];
    #pragma unroll
    for (int nf = 0; nf < 2; nf++)
        #pragma unroll
        for (int ks = 0; ks < 2; ks++) {
            int n = w * 32 + nf * 16 + lr;
            int cl = (ks * 4 + lk) ^ (lr & 7);
            gB[nf][ks] = w1pt + (size_t)n * H2_PER_S + cl * 8;
        }
    // A read offsets (XOR undoes h2's physical swizzle; row mod 8 == lr mod 8)
    int aoff[2][2];
    #pragma unroll
    for (int ks = 0; ks < 2; ks++) {
        int cl = (ks * 4 + lk);
        #pragma unroll
        for (int mf = 0; mf < 2; mf++)
            aoff[mf][ks] = (mf * 16 + lr) * 64 + ((cl ^ (lr & 7)) << 3);
    }

    f32x4 acc[2][2] = {};
    short8 b0[2][2], b1[2][2];
    // prologue: stage A(0) -> lA0, load B(0) -> b0
    if (stager) gl_lds16(ga, lA0 + saOff);
    ga += 64;
    #pragma unroll
    for (int nf = 0; nf < 2; nf++)
        #pragma unroll
        for (int ks = 0; ks < 2; ks++) { b0[nf][ks] = *(const short8*)gB[nf][ks]; gB[nf][ks] += 64; }
    __syncthreads();

    #define K3_COMPUTE(LA, BB)                                                              \
        _Pragma("unroll")                                                                   \
        for (int ks = 0; ks < 2; ks++) {                                                    \
            short8 a[2];                                                                    \
            _Pragma("unroll")                                                               \
            for (int mf = 0; mf < 2; mf++) a[mf] = *(const short8*)&(LA)[aoff[mf][ks]];     \
            _Pragma("unroll")                                                               \
            for (int mf = 0; mf < 2; mf++)                                                  \
                _Pragma("unroll")                                                           \
                for (int nf = 0; nf < 2; nf++)                                              \
                    acc[mf][nf] = __builtin_amdgcn_mfma_f32_16x16x32_bf16(a[mf], (BB)[nf][ks], acc[mf][nf], 0, 0, 0); \
        }

    for (int kt2 = 0; kt2 < 40; kt2++) {
        // even kt: compute lA0/b0; prefetch kt+1 -> lA1/b1
        if (stager) gl_lds16(ga, lA1 + saOff);
        ga += 64;
        #pragma unroll
        for (int nf = 0; nf < 2; nf++)
            #pragma unroll
            for (int ks = 0; ks < 2; ks++) { b1[nf][ks] = *(const short8*)gB[nf][ks]; gB[nf][ks] += 64; }
        K3_COMPUTE(lA0, b0);
        __syncthreads();
        // odd kt+1: compute lA1/b1; prefetch kt+2 -> lA0/b0
        if (kt2 < 39) {
            if (stager) gl_lds16(ga, lA0 + saOff);
            ga += 64;
            #pragma unroll
            for (int nf = 0; nf < 2; nf++)
                #pragma unroll
                for (int ks = 0; ks < 2; ks++) { b0[nf][ks] = *(const short8*)gB[nf][ks]; gB[nf][ks] += 64; }
        }
        K3_COMPUTE(lA1, b1);
        __syncthreads();
    }
    #undef K3_COMPUTE
    // fc1 epilogue: bias + speed rank-1 + relu -> lH (aliases lA; all reads done)
    #pragma unroll
    for (int mf = 0; mf < 2; mf++) {
        #pragma unroll
        for (int j = 0; j < 4; j++) {
            int r = mf * 16 + lk * 4 + j;
            float sp = sspeed[r];
            #pragma unroll
            for (int nf = 0; nf < 2; nf++) {
                int col = w * 32 + nf * 16 + lr;
                float v = acc[mf][nf][j] + sbias[col] + sp * swl[col];
                int cc = col >> 3, cl = col & 7;
                lH[r * 256 + ((cc ^ (r & 7)) << 3) + cl] = f2bf(v > 0.f ? v : 0.f);
            }
        }
    }
    __syncthreads();
    // fc2: M=32, N=128, K=256. 8 waves: rows wm*16 (1 tile), cols wn*32 (2 nf2 tiles). acc2[2]
    f32x4 acc2[2] = {};
    #pragma unroll
    for (int ks2 = 0; ks2 < 8; ks2++) {
        int row = wm * 16 + lr;
        int chunk = (ks2 * 4 + lk) ^ (row & 7);
        short8 a2 = *(const short8*)&lH[row * 256 + chunk * 8];
        #pragma unroll
        for (int nf2 = 0; nf2 < 2; nf2++) {
            short8 bv = *(const short8*)&w2bt[(size_t)(wn * 32 + nf2 * 16 + lr) * 256 + ks2 * 32 + lk * 8];
            acc2[nf2] = __builtin_amdgcn_mfma_f32_16x16x32_bf16(a2, bv, acc2[nf2], 0, 0, 0);
        }
    }
    // fc3: relu(fc2+b2) dot w3; per-lane partials, 16-lane reduce, cross-wave via pf
    float p3[4][3];
    #pragma unroll
    for (int j = 0; j < 4; j++)
        #pragma unroll
        for (int o = 0; o < 3; o++) p3[j][o] = 0.f;
    #pragma unroll
    for (int nf2 = 0; nf2 < 2; nf2++) {
        int col = wn * 32 + nf2 * 16 + lr;
        float w0 = sw3[col * 3 + 0], w1v = sw3[col * 3 + 1], w2v = sw3[col * 3 + 2];
        #pragma unroll
        for (int j = 0; j < 4; j++) {
            float v = acc2[nf2][j] + sb2[col];
            v = v > 0.f ? v : 0.f;
            p3[j][0] += v * w0;
            p3[j][1] += v * w1v;
            p3[j][2] += v * w2v;
        }
    }
    #pragma unroll
    for (int off = 1; off < 16; off <<= 1)
        #pragma unroll
        for (int j = 0; j < 4; j++)
            #pragma unroll
            for (int o = 0; o < 3; o++)
                p3[j][o] += __shfl_xor(p3[j][o], off);
    if (lr == 0) {
        #pragma unroll
        for (int j = 0; j < 4; j++) {
            int r = wm * 16 + lk * 4 + j;
            #pragma unroll
            for (int o = 0; o < 3; o++) pf[wn][r][o] = p3[j][o];
        }
    }
    __syncthreads();
    if (tid < 96) {
        int r = tid / 3, o = tid - r * 3;
        out[(size_t)(s0 + bm * 32 + r) * 3 + o] =
            pf[0][r][o] + pf[1][r][o] + pf[2][r][o] + pf[3][r][o] + f3b[o];
    }
}

// ---------- launcher ----------
extern "C" void kernel_launch(void* const* d_in, const int* in_sizes, int n_in,
                              void* d_out, int out_size, void* d_ws, size_t ws_size,
                              hipStream_t stream) {
    const float* x   = (const float*)d_in[0];
    const float* c1w = (const float*)d_in[1];
    const float* c1b = (const float*)d_in[2];
    const float* c2w = (const float*)d_in[3];
    const float* c2b = (const float*)d_in[4];
    const float* f1w = (const float*)d_in[5];
    const float* f1b = (const float*)d_in[6];
    const float* f2w = (const float*)d_in[7];
    const float* f2b = (const float*)d_in[8];
    const float* f3w = (const float*)d_in[9];
    const float* f3b = (const float*)d_in[10];
    float* out = (float*)d_out;

    char* ws = (char*)d_ws;
    uint16_t* w1pt = (uint16_t*)ws;                        // 256*5120*2 = 2,621,440 B
    uint16_t* w2rt = (uint16_t*)(ws + 2621440);            // 10,240 B
    uint16_t* w2bt = (uint16_t*)(ws + 2631680);            // 65,536 B
    uint16_t* w1rt = (uint16_t*)(ws + 2697216);            // 1,024 B
    size_t base = 2698240;

    // per-sample ws: h2 = 5120*2 = 10,240 B
    int chunk = NSAMP_TOT;
    while (chunk > 128 && base + (size_t)chunk * 10240 > ws_size) chunk >>= 1;
    uint16_t* h2 = (uint16_t*)(ws + base);

    repack_all<<<169, 256, 0, stream>>>(f1w, c2w, c1w, f2w, w1pt, w2rt, w1rt, w2bt);

    for (int s0 = 0; s0 < NSAMP_TOT; s0 += chunk) {
        k12_fused<<<chunk / 8, 512, 0, stream>>>(x, w1rt, c1b, w2rt, c2b, h2, s0);
        k3_fused<<<chunk / 32, 512, 0, stream>>>(h2, w1pt, f1b, f1w, x, w2bt, f2b, f3w, f3b, out, s0);
    }
}

// Round 23
// 263.985 us; speedup vs baseline: 1.2895x; 1.2895x over previous
//
#include <hip/hip_runtime.h>
#include <hip/hip_bf16.h>
#include <stdint.h>

// ---------- types / helpers ----------
typedef short short8 __attribute__((ext_vector_type(8)));   // 8 x bf16 (4 VGPRs) MFMA frag
typedef float f32x4  __attribute__((ext_vector_type(4)));   // MFMA C/D frag

__device__ __forceinline__ uint16_t f2bf(float f) {
    union { float f; uint32_t u; } v; v.f = f;
    return (uint16_t)((v.u + 0x7FFFu + ((v.u >> 16) & 1u)) >> 16);  // RNE
}
__device__ __forceinline__ float bf2f(uint16_t h) {
    union { uint32_t u; float f; } v; v.u = ((uint32_t)h) << 16;
    return v.f;
}
// pack 2 f32 -> 2 bf16 in one VALU op (lo = a, hi = b)
__device__ __forceinline__ uint32_t pk2bf(float a, float b) {
    uint32_t r;
    asm("v_cvt_pk_bf16_f32 %0, %1, %2" : "=v"(r) : "v"(a), "v"(b));
    return r;
}
// async global->LDS, 16B per lane. LDS dest must be wave-uniform base + lane*16.
__device__ __forceinline__ void gl_lds16(const void* g, void* l) {
    __builtin_amdgcn_global_load_lds(
        (const __attribute__((address_space(1))) unsigned int*)g,
        (__attribute__((address_space(3))) unsigned int*)l, 16, 0, 0);
}

#define NSAMP_TOT 32768
// h2 LOGICAL layout: [s][k'], k' = (p/16)*512 + c*16 + (p%16), K padded to 5120.
// h2 PHYSICAL: within each 64-elem K-window, 8-elem chunk q holds logical chunk q ^ (s&7).
// w1pt PHYSICAL: within each 64-elem K-window, chunk q holds logical chunk q ^ (n&7).
#define H2_PER_S  5120

// ---------- K0: all weight repacks in one dispatch (169 blocks) ----------
__global__ void repack_all(const float* __restrict__ f1w, const float* __restrict__ c2w,
                           const float* __restrict__ c1w, const float* __restrict__ f2w,
                           uint16_t* __restrict__ w1pt, uint16_t* __restrict__ w2rt,
                           uint16_t* __restrict__ w1rt, uint16_t* __restrict__ w2bt) {
    int tid = threadIdx.x, b = blockIdx.x;
    if (b < 160) {
        int f_s = b >> 4, cp = b & 15, n = tid;
        __align__(16) uint16_t vals[32];
        #pragma unroll
        for (int o = 0; o < 32; o++) {
            int c = cp * 2 + (o >> 4), pl = o & 15;
            int p = f_s * 16 + pl;
            float v = (p < 150) ? f1w[(size_t)(c * 150 + p) * 256 + n] : 0.f;  // coalesced over n
            vals[o] = f2bf(v);
        }
        int win = f_s * 8 + (cp >> 1);
        size_t rowbase = (size_t)n * H2_PER_S + win * 64;
        #pragma unroll
        for (int j = 0; j < 4; j++) {
            int qlog = (cp * 4 + j) & 7;
            int qphy = qlog ^ (n & 7);
            *(uint4*)&w1pt[rowbase + qphy * 8] = *(uint4*)&vals[j * 8];
        }
    } else if (b == 160) {
        for (int t = tid; t < 32 * 160; t += 256) {
            int n = t / 160, k = t % 160;
            float v = 0.f;
            if (k < 144) {
                int tap = k >> 4, ci = k & 15, dy = tap / 3, dx = tap % 3;
                v = c2w[((n * 16 + ci) * 3 + dy) * 3 + dx];
            }
            w2rt[t] = f2bf(v);
        }
        for (int t = tid; t < 16 * 32; t += 256) {
            int n = t >> 5, k = t & 31;
            float v = 0.f;
            if (k < 18) {
                int tap = k >> 1, ch = k & 1;
                int dy = (tap * 11) >> 5, dx = tap - dy * 3;
                v = c1w[((n * 2 + ch) * 3 + dy) * 3 + dx];
            }
            w1rt[t] = f2bf(v);
        }
    } else {
        __shared__ float tr2[32][129];
        int kb = b - 161;                         // 0..7
        for (int i = tid; i < 32 * 128; i += 256) {
            int kk = i >> 7, n = i & 127;
            tr2[kk][n] = f2w[(size_t)(kb * 32 + kk) * 128 + n];
        }
        __syncthreads();
        int n = tid >> 1, half = tid & 1;
        __align__(16) uint16_t tmp[16];
        #pragma unroll
        for (int q = 0; q < 16; q++) tmp[q] = f2bf(tr2[half * 16 + q][n]);
        *(uint4*)&w2bt[(size_t)n * 256 + kb * 32 + half * 16]     = *(uint4*)&tmp[0];
        *(uint4*)&w2bt[(size_t)n * 256 + kb * 32 + half * 16 + 8] = *(uint4*)&tmp[8];
    }
}

// ---------- K12: grid scatter + conv1 MFMA + conv2 MFMA + relu -> h2 (swizzled chunks) ----------
// 8 samples/block, 512 threads (8 waves). WAVE w OWNS SAMPLE w. LUTs replace divisions.
// HBM-write-bound at ~4.7 TB/s -- at ceiling.
__launch_bounds__(512, 2)
__global__ void k12_fused(const float* __restrict__ x, const uint16_t* __restrict__ w1rt,
                          const float* __restrict__ c1b, const uint16_t* __restrict__ w2rt,
                          const float* __restrict__ c2b, uint16_t* __restrict__ h2, int s0) {
    __shared__ float sx[8 * 42];                           // 1344 B
    __shared__ __align__(16) uint16_t grd[8 * 204 * 2];    // 6528 B  = 408 uint4
    __shared__ __align__(16) uint16_t h1s[8 * 205 * 16];   // 52480 B = 3280 uint4
    __shared__ uint16_t lutPO[160];
    __shared__ uint16_t lutST[160];
    int tid = threadIdx.x;
    int w = tid >> 6, l = tid & 63, lr = l & 15, lk = l >> 4;

    short8 b1f = *(const short8*)&w1rt[lr * 32 + lk * 8];
    short8 bfr[5][2];
    #pragma unroll
    for (int ks = 0; ks < 5; ks++)
        #pragma unroll
        for (int nf = 0; nf < 2; nf++)
            bfr[ks][nf] = *(const short8*)&w2rt[(nf * 16 + lr) * 160 + ks * 32 + lk * 8];
    float cb1r = c1b[lr];
    float cb0 = c2b[lr], cb1 = c2b[16 + lr];

    uint4 z4 = make_uint4(0, 0, 0, 0);
    for (int idx = tid; idx < 3688; idx += 512) {
        if (idx < 408) ((uint4*)grd)[idx] = z4;
        else           ((uint4*)h1s)[idx - 408] = z4;
    }
    int sbase = s0 + blockIdx.x * 8;
    if (tid < 336) sx[tid] = x[(size_t)(sbase + tid / 42) * 42 + (tid % 42)];
    if (tid >= 336 && tid < 496) {
        int p = tid - 336;
        int y = p / 15, xx = p - y * 15;
        int po = y * 17 + xx;
        lutPO[p] = (p < 150) ? (uint16_t)po : 0;
        lutST[p] = (p < 150) ? (uint16_t)((po + 18) * 16) : (uint16_t)(204 * 16);
    }
    __syncthreads();

    if (tid < 160) {
        int sl = tid / 20, r = tid % 20;
        int kx = (int)sx[sl * 42 + 1 + 2 * r];
        int ky = (int)sx[sl * 42 + 2 + 2 * r];
        if (kx >= 0 && kx < 15 && ky >= 0 && ky < 10)
            grd[(sl * 204 + (ky + 1) * 17 + (kx + 1)) * 2 + 1] = 0x3F80;  // 1.0 bf16
    } else if (tid < 168) {
        int sl = tid - 160;
        int ry = (int)sx[sl * 42];
        if (ry >= 0 && ry < 10)
            grd[(sl * 204 + (ry + 1) * 17 + 2) * 2 + 0] = 0x3F80;
    }
    __syncthreads();

    int goff[4]; uint32_t gmask[4];
    #pragma unroll
    for (int jj = 0; jj < 4; jj++) {
        int t = lk * 4 + jj;
        int tc = t < 9 ? t : 0;
        int dy = (tc * 11) >> 5, dx = tc - dy * 3;
        goff[jj] = dy * 17 + dx;
        gmask[jj] = (t < 9) ? 0xFFFFFFFFu : 0u;
    }
    int sbg  = w * 204;
    int sb16 = w * 205 * 16;

    #pragma unroll
    for (int f_s = 0; f_s < 10; f_s++) {
        int p160 = f_s * 16 + lr;
        int gbase = sbg + lutPO[p160];
        union { uint32_t d[4]; short8 s; } au;
        #pragma unroll
        for (int jj = 0; jj < 4; jj++) {
            uint32_t v = *(const uint32_t*)&grd[(gbase + goff[jj]) * 2];
            au.d[jj] = v & gmask[jj];
        }
        f32x4 acc = {};
        acc = __builtin_amdgcn_mfma_f32_16x16x32_bf16(au.s, b1f, acc, 0, 0, 0);
        #pragma unroll
        for (int j = 0; j < 4; j += 2) {
            float v0 = fmaxf(acc[j] + cb1r, 0.f);
            float v1 = fmaxf(acc[j + 1] + cb1r, 0.f);
            uint32_t pk = pk2bf(v0, v1);
            int p2 = f_s * 16 + lk * 4 + j;
            h1s[sb16 + lutST[p2] + lr]     = (uint16_t)pk;
            h1s[sb16 + lutST[p2 + 1] + lr] = (uint16_t)(pk >> 16);
        }
    }
    __syncthreads();

    int cdofs[5];
    #pragma unroll
    for (int ks = 0; ks < 5; ks++) {
        int idx = ks * 4 + lk;
        int idc = idx < 18 ? idx : 0;
        int tap = idc >> 1, half = idc & 1;
        int dy = (tap * 11) >> 5, dx = tap - dy * 3;
        cdofs[ks] = (dy * 17 + dx) * 16 + half * 8;
    }
    uint32_t kmask4 = ((16 + lk) < 18) ? 0xFFFFFFFFu : 0u;
    int k0lo = lr * 16 + lk * 4;
    int k0s_base = (k0lo & ~63) | ((((k0lo >> 3) & 7) ^ w) << 3) | (k0lo & 7);
    size_t sbh2 = (size_t)(blockIdx.x * 8 + w) * H2_PER_S;

    #pragma unroll
    for (int f_s = 0; f_s < 10; f_s++) {
        int p160 = f_s * 16 + lr;
        int abase = sb16 + lutPO[p160] * 16;
        f32x4 acc0 = {}, acc1 = {};
        #pragma unroll
        for (int ks = 0; ks < 5; ks++) {
            short8 av = *(const short8*)&h1s[abase + cdofs[ks]];
            if (ks == 4) {
                union { short8 s; uint32_t d[4]; } u; u.s = av;
                #pragma unroll
                for (int dd = 0; dd < 4; dd++) u.d[dd] &= kmask4;
                av = u.s;
            }
            acc0 = __builtin_amdgcn_mfma_f32_16x16x32_bf16(av, bfr[ks][0], acc0, 0, 0, 0);
            acc1 = __builtin_amdgcn_mfma_f32_16x16x32_bf16(av, bfr[ks][1], acc1, 0, 0, 0);
        }
        uint32_t p01 = pk2bf(fmaxf(acc0[0] + cb0, 0.f), fmaxf(acc0[1] + cb0, 0.f));
        uint32_t p23 = pk2bf(fmaxf(acc0[2] + cb0, 0.f), fmaxf(acc0[3] + cb0, 0.f));
        uint32_t q01 = pk2bf(fmaxf(acc1[0] + cb1, 0.f), fmaxf(acc1[1] + cb1, 0.f));
        uint32_t q23 = pk2bf(fmaxf(acc1[2] + cb1, 0.f), fmaxf(acc1[3] + cb1, 0.f));
        int k0s = f_s * 512 + k0s_base;
        *(uint2*)&h2[sbh2 + k0s]       = make_uint2(p01, p23);
        *(uint2*)&h2[sbh2 + k0s + 256] = make_uint2(q01, q23);
    }
}

// ---------- K3: fc1 (64x256, K=5120, R12 2-buffer dbuf schedule) + fc2 + fc3 ----------
// 512 threads = 8 waves (2M x 4N), per-wave 32x64 acc[2][4]. grid = chunk/64 = full machine.
// Body kt: [stage kt+1 -> buf^1] [compute buf] [__syncthreads].  Best measured config
// (R20: 264.4us total). Race-free: buf^1's readers passed the end-of-kt-1 barrier.
__launch_bounds__(512)
__global__ void k3_fused(const uint16_t* __restrict__ h2, const uint16_t* __restrict__ w1pt,
                         const float* __restrict__ f1b, const float* __restrict__ f1w,
                         const float* __restrict__ x, const uint16_t* __restrict__ w2bt,
                         const float* __restrict__ f2b, const float* __restrict__ f3w,
                         const float* __restrict__ f3b, float* __restrict__ out, int s0) {
    #define BUF_E (64 * 64 + 256 * 64)                      // 20480 elems / buffer
    __shared__ __align__(16) uint16_t uLDS[2 * BUF_E];      // 81,920 B
    uint16_t* lH = uLDS;                                    // 64 x 256 epilogue reuse (32 KB)
    __shared__ float sbias[256], swl[256], sspeed[64], sb2[128], sw3[384];
    __shared__ float pf[4][64][3];
    int tid = threadIdx.x;
    int bm = blockIdx.x;
    if (tid < 256) { sbias[tid] = f1b[tid]; swl[tid] = f1w[(size_t)4800 * 256 + tid]; }
    else if (tid < 320) sspeed[tid - 256] = x[(size_t)(s0 + bm * 64 + (tid - 256)) * 42 + 41];
    else if (tid < 448) sb2[tid - 320] = f2b[tid - 320];
    for (int i = tid; i < 384; i += 512) sw3[i] = f3w[i];

    int w = tid >> 6, l = tid & 63, lr = l & 15, lk = l >> 4;
    int wm = w >> 2, wn = w & 3;
    const uint16_t* ga = &h2[(size_t)(bm * 64 + (tid >> 3)) * H2_PER_S + (tid & 7) * 8];
    const uint16_t* gb[4];
    #pragma unroll
    for (int i = 0; i < 4; i++) {
        int c2 = tid + i * 512;
        gb[i] = &w1pt[(size_t)(c2 >> 3) * H2_PER_S + (c2 & 7) * 8];
    }
    int saOff = tid * 8;
    int sbOff[4];
    #pragma unroll
    for (int i = 0; i < 4; i++) sbOff[i] = 4096 + (tid + i * 512) * 8;
    int aoff[2][2], boff[4][2];
    #pragma unroll
    for (int ks = 0; ks < 2; ks++) {
        int cl = (ks * 4 + lk);
        #pragma unroll
        for (int mf = 0; mf < 2; mf++)
            aoff[mf][ks] = (wm * 32 + mf * 16 + lr) * 64 + ((cl ^ (lr & 7)) << 3);
        #pragma unroll
        for (int nf = 0; nf < 4; nf++)
            boff[nf][ks] = 4096 + (wn * 64 + nf * 16 + lr) * 64 + ((cl ^ (lr & 7)) << 3);
    }

    f32x4 acc[2][4] = {};
    // prologue: stage kt=0 into buf0
    gl_lds16(ga, uLDS + saOff); ga += 64;
    #pragma unroll
    for (int i = 0; i < 4; i++) { gl_lds16(gb[i], uLDS + sbOff[i]); gb[i] += 64; }
    __syncthreads();
    for (int kt = 0; kt < 80; kt++) {
        int cur = kt & 1;
        uint16_t* nbuf = uLDS + (cur ^ 1) * BUF_E;
        if (kt < 79) {   // stage kt+1 first; latency hides under compute below
            gl_lds16(ga, nbuf + saOff); ga += 64;
            #pragma unroll
            for (int i = 0; i < 4; i++) { gl_lds16(gb[i], nbuf + sbOff[i]); gb[i] += 64; }
        }
        const uint16_t* buf = uLDS + cur * BUF_E;
        #pragma unroll
        for (int ks = 0; ks < 2; ks++) {
            short8 a[2], b[4];
            #pragma unroll
            for (int mf = 0; mf < 2; mf++)
                a[mf] = *(const short8*)&buf[aoff[mf][ks]];
            #pragma unroll
            for (int nf = 0; nf < 4; nf++)
                b[nf] = *(const short8*)&buf[boff[nf][ks]];
            #pragma unroll
            for (int mf = 0; mf < 2; mf++)
                #pragma unroll
                for (int nf = 0; nf < 4; nf++)
                    acc[mf][nf] = __builtin_amdgcn_mfma_f32_16x16x32_bf16(a[mf], b[nf], acc[mf][nf], 0, 0, 0);
        }
        __syncthreads();  // drains next-tile stage (vmcnt0) + guards buffer reuse
    }
    // fc1 epilogue: bias + speed rank-1 + relu -> lH (aliases buffers; all reads done)
    #pragma unroll
    for (int mf = 0; mf < 2; mf++) {
        #pragma unroll
        for (int j = 0; j < 4; j++) {
            int r = wm * 32 + mf * 16 + lk * 4 + j;
            float sp = sspeed[r];
            #pragma unroll
            for (int nf = 0; nf < 4; nf++) {
                int col = wn * 64 + nf * 16 + lr;
                float v = acc[mf][nf][j] + sbias[col] + sp * swl[col];
                int cc = col >> 3, cl = col & 7;
                lH[r * 256 + ((cc ^ (r & 7)) << 3) + cl] = f2bf(v > 0.f ? v : 0.f);
            }
        }
    }
    __syncthreads();
    // fc2: M=64, N=128, K=256. 8 waves: rows wm*32, cols wn*32. acc2[2][2]
    f32x4 acc2[2][2] = {};
    #pragma unroll
    for (int ks2 = 0; ks2 < 8; ks2++) {
        short8 a2[2], bv[2];
        #pragma unroll
        for (int mf2 = 0; mf2 < 2; mf2++) {
            int row = wm * 32 + mf2 * 16 + lr;
            int chunk = (ks2 * 4 + lk) ^ (row & 7);
            a2[mf2] = *(const short8*)&lH[row * 256 + chunk * 8];
        }
        #pragma unroll
        for (int nf2 = 0; nf2 < 2; nf2++)
            bv[nf2] = *(const short8*)&w2bt[(size_t)(wn * 32 + nf2 * 16 + lr) * 256 + ks2 * 32 + lk * 8];
        #pragma unroll
        for (int mf2 = 0; mf2 < 2; mf2++)
            #pragma unroll
            for (int nf2 = 0; nf2 < 2; nf2++)
                acc2[mf2][nf2] = __builtin_amdgcn_mfma_f32_16x16x32_bf16(a2[mf2], bv[nf2], acc2[mf2][nf2], 0, 0, 0);
    }
    // fc3: relu(fc2+b2) dot w3; per-lane partials, 16-lane reduce, cross-wave via pf
    float p3[2][4][3];
    #pragma unroll
    for (int mf2 = 0; mf2 < 2; mf2++)
        #pragma unroll
        for (int j = 0; j < 4; j++)
            #pragma unroll
            for (int o = 0; o < 3; o++) p3[mf2][j][o] = 0.f;
    #pragma unroll
    for (int mf2 = 0; mf2 < 2; mf2++) {
        #pragma unroll
        for (int nf2 = 0; nf2 < 2; nf2++) {
            int col = wn * 32 + nf2 * 16 + lr;
            float w0 = sw3[col * 3 + 0], w1v = sw3[col * 3 + 1], w2v = sw3[col * 3 + 2];
            #pragma unroll
            for (int j = 0; j < 4; j++) {
                float v = acc2[mf2][nf2][j] + sb2[col];
                v = v > 0.f ? v : 0.f;
                p3[mf2][j][0] += v * w0;
                p3[mf2][j][1] += v * w1v;
                p3[mf2][j][2] += v * w2v;
            }
        }
    }
    #pragma unroll
    for (int off = 1; off < 16; off <<= 1)
        #pragma unroll
        for (int mf2 = 0; mf2 < 2; mf2++)
            #pragma unroll
            for (int j = 0; j < 4; j++)
                #pragma unroll
                for (int o = 0; o < 3; o++)
                    p3[mf2][j][o] += __shfl_xor(p3[mf2][j][o], off);
    if (lr == 0) {
        #pragma unroll
        for (int mf2 = 0; mf2 < 2; mf2++)
            #pragma unroll
            for (int j = 0; j < 4; j++) {
                int r = wm * 32 + mf2 * 16 + lk * 4 + j;
                #pragma unroll
                for (int o = 0; o < 3; o++) pf[wn][r][o] = p3[mf2][j][o];
            }
    }
    __syncthreads();
    if (tid < 192) {
        int r = tid / 3, o = tid - r * 3;
        out[(size_t)(s0 + bm * 64 + r) * 3 + o] =
            pf[0][r][o] + pf[1][r][o] + pf[2][r][o] + pf[3][r][o] + f3b[o];
    }
    #undef BUF_E
}

// ---------- launcher ----------
extern "C" void kernel_launch(void* const* d_in, const int* in_sizes, int n_in,
                              void* d_out, int out_size, void* d_ws, size_t ws_size,
                              hipStream_t stream) {
    const float* x   = (const float*)d_in[0];
    const float* c1w = (const float*)d_in[1];
    const float* c1b = (const float*)d_in[2];
    const float* c2w = (const float*)d_in[3];
    const float* c2b = (const float*)d_in[4];
    const float* f1w = (const float*)d_in[5];
    const float* f1b = (const float*)d_in[6];
    const float* f2w = (const float*)d_in[7];
    const float* f2b = (const float*)d_in[8];
    const float* f3w = (const float*)d_in[9];
    const float* f3b = (const float*)d_in[10];
    float* out = (float*)d_out;

    char* ws = (char*)d_ws;
    uint16_t* w1pt = (uint16_t*)ws;                        // 256*5120*2 = 2,621,440 B
    uint16_t* w2rt = (uint16_t*)(ws + 2621440);            // 10,240 B
    uint16_t* w2bt = (uint16_t*)(ws + 2631680);            // 65,536 B
    uint16_t* w1rt = (uint16_t*)(ws + 2697216);            // 1,024 B
    size_t base = 2698240;

    // per-sample ws: h2 = 5120*2 = 10,240 B
    int chunk = NSAMP_TOT;
    while (chunk > 128 && base + (size_t)chunk * 10240 > ws_size) chunk >>= 1;
    uint16_t* h2 = (uint16_t*)(ws + base);

    repack_all<<<169, 256, 0, stream>>>(f1w, c2w, c1w, f2w, w1pt, w2rt, w1rt, w2bt);

    for (int s0 = 0; s0 < NSAMP_TOT; s0 += chunk) {
        k12_fused<<<chunk / 8, 512, 0, stream>>>(x, w1rt, c1b, w2rt, c2b, h2, s0);
        k3_fused<<<chunk / 64, 512, 0, stream>>>(h2, w1pt, f1b, f1w, x, w2bt, f2b, f3w, f3b, out, s0);
    }
}